// Round 12
// baseline (2991.007 us; speedup 1.0000x reference)
//
#include <hip/hip_runtime.h>

#define Hd 128
#define Tn 1024
#define Dn 5
#define Ln 16
#define Bn 512
// Quarter-gapped hidden layout: quarter q (32 floats) lives at float offset
// 36*q. The 4 per-wave broadcast addresses (kq=0..3) then land on banks
// {4k,4k+4,4k+8,4k+12} mod 32 -> four DISJOINT bank quads, conflict-free
// (round 10: SQ_LDS_BANK_CONFLICT 2.7e6, negligible).
#define QP 36
#define HP4 144
#define GF(f) ((f) + (((f) >> 5) << 2))            // linear h index -> gapped
#define CF(q) (QP * ((q) >> 3) + 4 * ((q) & 7))    // float4 chunk -> gapped

__device__ __forceinline__ float sigm(float x) { return 1.0f / (1.0f + __expf(-x)); }
__device__ __forceinline__ float tanh_fast(float x) { return 1.0f - 2.0f / (1.0f + __expf(2.0f * x)); }

#define RED4(v) { v += __shfl_xor(v, 1); v += __shfl_xor(v, 2); }

// Persistent GRU autoencoder, K-split-by-4 layout.
// grid = 512 WGs (1 batch row each), block = 512 threads (8 waves).
// Thread (j,kq)=(tid>>2,tid&3) owns QUARTER kq of W_hh rows {j,128+j,256+j}
// = 24 float4 = 96 VGPRs; total live ~121-126.
// REGISTER LAW (measured rounds 2/9/10): gfx950 compiler splits the unified
// 512-reg/wave-budget file 50/50 arch/AGPR: LB(256,1)->256 arch, (2,2)->128,
// (4,4)->64. Demand must fit budget/2 or weights spill to scratch (round 10:
// (4,4) gave arch=64 < 121 -> 127 MB scratch writes, VALUBusy 91% of moves).
// So: waves_per_eu(2,2) -> arch 128 >= 126 demand -> clean code. 1 WG/CU,
// 512 WGs run as 2 sequential generations (WGs independent, no sync needed).
__global__ __launch_bounds__(512)
__attribute__((amdgpu_waves_per_eu(2, 2)))
void gru_ae_kernel(
    const float* __restrict__ x,
    const float* __restrict__ eWih, const float* __restrict__ eWhh,
    const float* __restrict__ ebih, const float* __restrict__ ebhh,
    const float* __restrict__ efcW, const float* __restrict__ efcb,
    const float* __restrict__ dfcW, const float* __restrict__ dfcb,
    const float* __restrict__ dWih, const float* __restrict__ dWhh,
    const float* __restrict__ dbih, const float* __restrict__ dbhh,
    const float* __restrict__ oW, const float* __restrict__ ob,
    float* __restrict__ out)
{
    __shared__ __align__(16) float henc[2][HP4];   // ping-pong encoder h (gapped)
    __shared__ __align__(16) float hs[32][HP4];    // decoder 32-step h history (gapped)
    __shared__ __align__(16) float hdi[HP4];       // decoder input-hidden (gapped)
    __shared__ float zl[Ln];                       // latent z

    const int tid = threadIdx.x;
    const int j   = tid >> 2;       // hidden index 0..127
    const int kq  = tid & 3;        // K-quarter 0..3
    const int b   = blockIdx.x;     // one batch row per WG
    const int koff = kq * 32;       // global float offset of quarter
    const int klds = kq * QP;       // gapped LDS offset of quarter

    // ---- encoder W_hh quarter-rows into registers (96 VGPRs) ----
    float4 wr[8], wz[8], wn[8];
    {
        const float4* p0 = (const float4*)(eWhh + (size_t)j * Hd + koff);
        const float4* p1 = (const float4*)(eWhh + (size_t)(Hd + j) * Hd + koff);
        const float4* p2 = (const float4*)(eWhh + (size_t)(2 * Hd + j) * Hd + koff);
#pragma unroll
        for (int k = 0; k < 8; ++k) { wr[k] = p0[k]; wz[k] = p1[k]; wn[k] = p2[k]; }
    }
    // x-projection split across the quad: kq0 d={0,1}, kq1 d={2,3}, kq2 d={4}, kq3 none
    const int d0s = (kq == 1) ? 2 : (kq == 2) ? 4 : 0;
    const int inc = (kq < 2) ? 1 : 0;
    const float m0 = (kq < 3) ? 1.f : 0.f, m1 = (kq < 2) ? 1.f : 0.f;
    float wxr0 = m0 * eWih[(size_t)j * Dn + d0s];
    float wxr1 = m1 * eWih[(size_t)j * Dn + d0s + inc];
    float wxz0 = m0 * eWih[(size_t)(Hd + j) * Dn + d0s];
    float wxz1 = m1 * eWih[(size_t)(Hd + j) * Dn + d0s + inc];
    float wxn0 = m0 * eWih[(size_t)(2 * Hd + j) * Dn + d0s];
    float wxn1 = m1 * eWih[(size_t)(2 * Hd + j) * Dn + d0s + inc];

    float bR = ebih[j] + ebhh[j];
    float bZ = ebih[Hd + j] + ebhh[Hd + j];
    float bihn = ebih[2 * Hd + j];
    float bhhn = ebhh[2 * Hd + j];

    if (tid < Hd) { henc[0][GF(tid)] = 0.f; henc[1][GF(tid)] = 0.f; }
    __syncthreads();

    float h_self = 0.f;
    int p = 0;
    const float* xrow = x + (size_t)b * Tn * Dn;
    float xc0 = xrow[d0s], xc1 = xrow[d0s + inc];

    // ================= encoder: 1024 steps, 1 barrier/step =================
#pragma unroll 1
    for (int t = 0; t < Tn; ++t) {
        // prefetch next step's x pair (lands during the 96-FMA block)
        const int off = ((t + 1 < Tn) ? (t + 1) : (Tn - 1)) * Dn;
        float nx0 = xrow[off + d0s], nx1 = xrow[off + d0s + inc];

        const float4* hv = (const float4*)&henc[p][klds];
        float ar = 0.f, az = 0.f, nh = 0.f;
#pragma unroll
        for (int k = 0; k < 8; ++k) {
            float4 h4 = hv[k];
            ar = fmaf(wr[k].x, h4.x, ar); az = fmaf(wz[k].x, h4.x, az); nh = fmaf(wn[k].x, h4.x, nh);
            ar = fmaf(wr[k].y, h4.y, ar); az = fmaf(wz[k].y, h4.y, az); nh = fmaf(wn[k].y, h4.y, nh);
            ar = fmaf(wr[k].z, h4.z, ar); az = fmaf(wz[k].z, h4.z, az); nh = fmaf(wn[k].z, h4.z, nh);
            ar = fmaf(wr[k].w, h4.w, ar); az = fmaf(wz[k].w, h4.w, az); nh = fmaf(wn[k].w, h4.w, nh);
        }
        // x partials (r,z fold into the h-dot; n's x-part reduces separately)
        ar = fmaf(wxr0, xc0, fmaf(wxr1, xc1, ar));
        az = fmaf(wxz0, xc0, fmaf(wxz1, xc1, az));
        float nx = fmaf(wxn0, xc0, wxn1 * xc1);
        RED4(ar); RED4(az); RED4(nh); RED4(nx);
        float r  = sigm(ar + bR);
        float zg = sigm(az + bZ);
        float n  = tanh_fast(nx + bihn + r * (nh + bhhn));
        float hnew = fmaf(zg, h_self - n, n);   // (1-z)*n + z*h
        h_self = hnew;
        if (!kq) henc[p ^ 1][GF(j)] = hnew;
        xc0 = nx0; xc1 = nx1;
        __syncthreads();
        p ^= 1;
    }

    // ================= latent z =================
    if (tid < Ln) {
        const float4* wp = (const float4*)(efcW + (size_t)tid * Hd);
        float acc = efcb[tid];
#pragma unroll
        for (int q = 0; q < 32; ++q) {
            float4 w4 = wp[q];
            float4 h4 = *(const float4*)&henc[p][CF(q)];
            acc = fmaf(w4.x, h4.x, fmaf(w4.y, h4.y, fmaf(w4.z, h4.z, fmaf(w4.w, h4.w, acc))));
        }
        out[(size_t)Bn * Tn * Dn + (size_t)b * Ln + tid] = acc;
        zl[tid] = acc;
    }
    __syncthreads();

    // ================= h_dec_in = z @ dec_fc_W.T + dec_fc_b =================
    if (tid < Hd) {
        const float4* wp = (const float4*)(dfcW + (size_t)tid * Ln);
        float acc = dfcb[tid];
#pragma unroll
        for (int l = 0; l < 4; ++l) {
            float4 w4 = wp[l];
            acc = fmaf(w4.x, zl[4 * l + 0], acc);
            acc = fmaf(w4.y, zl[4 * l + 1], acc);
            acc = fmaf(w4.z, zl[4 * l + 2], acc);
            acc = fmaf(w4.w, zl[4 * l + 3], acc);
        }
        hdi[GF(tid)] = acc;
    }
    __syncthreads();

    // ================= xp_dec (constant over decoder steps) =================
    float xdr, xdz, xdn;
    {
        const float4* p0 = (const float4*)(dWih + (size_t)j * Hd + koff);
        const float4* p1 = (const float4*)(dWih + (size_t)(Hd + j) * Hd + koff);
        const float4* p2 = (const float4*)(dWih + (size_t)(2 * Hd + j) * Hd + koff);
#pragma unroll
        for (int k = 0; k < 8; ++k) { wr[k] = p0[k]; wz[k] = p1[k]; wn[k] = p2[k]; }
        const float4* hv = (const float4*)&hdi[klds];
        float a0 = 0.f, a1 = 0.f, a2 = 0.f;
#pragma unroll
        for (int k = 0; k < 8; ++k) {
            float4 h4 = hv[k];
            a0 = fmaf(wr[k].x, h4.x, a0); a1 = fmaf(wz[k].x, h4.x, a1); a2 = fmaf(wn[k].x, h4.x, a2);
            a0 = fmaf(wr[k].y, h4.y, a0); a1 = fmaf(wz[k].y, h4.y, a1); a2 = fmaf(wn[k].y, h4.y, a2);
            a0 = fmaf(wr[k].z, h4.z, a0); a1 = fmaf(wz[k].z, h4.z, a1); a2 = fmaf(wn[k].z, h4.z, a2);
            a0 = fmaf(wr[k].w, h4.w, a0); a1 = fmaf(wz[k].w, h4.w, a1); a2 = fmaf(wn[k].w, h4.w, a2);
        }
        RED4(a0); RED4(a1); RED4(a2);
        xdr = a0 + dbih[j] + dbhh[j];
        xdz = a1 + dbih[Hd + j] + dbhh[Hd + j];
        xdn = a2 + dbih[2 * Hd + j];
        bhhn = dbhh[2 * Hd + j];
    }

    // ---- decoder W_hh quarter-rows ----
    {
        const float4* p0 = (const float4*)(dWhh + (size_t)j * Hd + koff);
        const float4* p1 = (const float4*)(dWhh + (size_t)(Hd + j) * Hd + koff);
        const float4* p2 = (const float4*)(dWhh + (size_t)(2 * Hd + j) * Hd + koff);
#pragma unroll
        for (int k = 0; k < 8; ++k) { wr[k] = p0[k]; wz[k] = p1[k]; wn[k] = p2[k]; }
    }

    if (tid < Hd) hs[31][GF(tid)] = 0.f;   // "previous h" for decoder step 0
    h_self = 0.f;
    __syncthreads();

    // ================= decoder: 1024 steps in 32-step tiles =================
#pragma unroll 1
    for (int s0 = 0; s0 < Tn; s0 += 32) {
#pragma unroll 1
        for (int ss = 0; ss < 32; ++ss) {
            const int ip = (ss + 31) & 31;
            const float4* hv = (const float4*)&hs[ip][klds];
            float ar = 0.f, az = 0.f, nh = 0.f;
#pragma unroll
            for (int k = 0; k < 8; ++k) {
                float4 h4 = hv[k];
                ar = fmaf(wr[k].x, h4.x, ar); az = fmaf(wz[k].x, h4.x, az); nh = fmaf(wn[k].x, h4.x, nh);
                ar = fmaf(wr[k].y, h4.y, ar); az = fmaf(wz[k].y, h4.y, az); nh = fmaf(wn[k].y, h4.y, nh);
                ar = fmaf(wr[k].z, h4.z, ar); az = fmaf(wz[k].z, h4.z, az); nh = fmaf(wn[k].z, h4.z, nh);
                ar = fmaf(wr[k].w, h4.w, ar); az = fmaf(wz[k].w, h4.w, az); nh = fmaf(wn[k].w, h4.w, nh);
            }
            RED4(ar); RED4(az); RED4(nh);
            float r  = sigm(xdr + ar);
            float zg = sigm(xdz + az);
            float n  = tanh_fast(xdn + r * (nh + bhhn));
            float hnew = fmaf(zg, h_self - n, n);
            h_self = hnew;
            if (!kq) hs[ss][GF(j)] = hnew;
            __syncthreads();
        }

        // ---- bulk recon projection for steps s0..s0+31 (coalesced stores) ----
        if (tid < 160) {
            const int i = tid / 5, d = tid % 5;
            const float4* wrow = (const float4*)(oW + (size_t)d * Hd);
            float ac0 = ob[d], ac1 = 0.f;
#pragma unroll
            for (int q = 0; q < 32; q += 2) {
                const int qa = (q + i) & 31, qb = (q + 1 + i) & 31;
                float4 ha = *(const float4*)&hs[i][CF(qa)];
                float4 wa = wrow[qa];
                float4 hb = *(const float4*)&hs[i][CF(qb)];
                float4 wb = wrow[qb];
                ac0 = fmaf(wa.x, ha.x, fmaf(wa.y, ha.y, fmaf(wa.z, ha.z, fmaf(wa.w, ha.w, ac0))));
                ac1 = fmaf(wb.x, hb.x, fmaf(wb.y, hb.y, fmaf(wb.z, hb.z, fmaf(wb.w, hb.w, ac1))));
            }
            out[((size_t)b * Tn + s0 + i) * Dn + d] = ac0 + ac1;
        }
        __syncthreads();   // protect hs before next tile overwrites slots
    }
}

extern "C" void kernel_launch(void* const* d_in, const int* in_sizes, int n_in,
                              void* d_out, int out_size, void* d_ws, size_t ws_size,
                              hipStream_t stream) {
    const float* x    = (const float*)d_in[0];
    const float* eWih = (const float*)d_in[1];
    const float* eWhh = (const float*)d_in[2];
    const float* ebih = (const float*)d_in[3];
    const float* ebhh = (const float*)d_in[4];
    const float* efcW = (const float*)d_in[5];
    const float* efcb = (const float*)d_in[6];
    const float* dfcW = (const float*)d_in[7];
    const float* dfcb = (const float*)d_in[8];
    const float* dWih = (const float*)d_in[9];
    const float* dWhh = (const float*)d_in[10];
    const float* dbih = (const float*)d_in[11];
    const float* dbhh = (const float*)d_in[12];
    const float* oW   = (const float*)d_in[13];
    const float* ob   = (const float*)d_in[14];
    float* out = (float*)d_out;

    gru_ae_kernel<<<dim3(Bn), dim3(512), 0, stream>>>(
        x, eWih, eWhh, ebih, ebhh, efcW, efcb, dfcW, dfcb,
        dWih, dWhh, dbih, dbhh, oW, ob, out);
}

// Round 13
// 2946.891 us; speedup vs baseline: 1.0150x; 1.0150x over previous
//
#include <hip/hip_runtime.h>

#define Hd 128
#define Tn 1024
#define Dn 5
#define Ln 16
#define Bn 512
// Quarter-gapped hidden layout: quarter q (32 floats) at float offset 36*q.
// The 4 per-wave broadcast addresses (kq=0..3) land on disjoint bank quads.
#define QP 36
#define HP4 144
#define GF(f) ((f) + (((f) >> 5) << 2))            // linear h index -> gapped
#define CF(q) (QP * ((q) >> 3) + 4 * ((q) & 7))    // float4 chunk -> gapped

__device__ __forceinline__ float sigm(float x) { return 1.0f / (1.0f + __expf(-x)); }
__device__ __forceinline__ float tanh_fast(float x) { return 1.0f - 2.0f / (1.0f + __expf(2.0f * x)); }

#define RED4(v) { v += __shfl_xor(v, 1); v += __shfl_xor(v, 2); }

// quarter-dot: 8 x float4 of h against the resident wr/wz/wn quarter-rows
#define QDOT(hv, AR, AZ, NH)                                                     \
    _Pragma("unroll")                                                            \
    for (int k = 0; k < 8; ++k) {                                                \
        float4 h4 = (hv)[k];                                                     \
        AR = fmaf(wr[k].x, h4.x, AR); AZ = fmaf(wz[k].x, h4.x, AZ); NH = fmaf(wn[k].x, h4.x, NH); \
        AR = fmaf(wr[k].y, h4.y, AR); AZ = fmaf(wz[k].y, h4.y, AZ); NH = fmaf(wn[k].y, h4.y, NH); \
        AR = fmaf(wr[k].z, h4.z, AR); AZ = fmaf(wz[k].z, h4.z, AZ); NH = fmaf(wn[k].z, h4.z, NH); \
        AR = fmaf(wr[k].w, h4.w, AR); AZ = fmaf(wz[k].w, h4.w, AZ); NH = fmaf(wn[k].w, h4.w, NH); \
    }

// Persistent GRU autoencoder, K-split-by-4, TWO rows per WG (shared weights).
// grid = 256 WGs (1/CU, SINGLE generation), block = 512 (8 waves, 2/SIMD).
// Thread (j,kq)=(tid>>2,tid&3) owns quarter kq of W_hh rows {j,128+j,256+j}
// = 96 VGPRs, shared by both batch rows (weights depend only on (j,kq)).
// Per step: two independent 96-FMA blocks (rows b0, b0+1) -> 2x ILP against
// the serial tail (barrier + LDS latency + reduce/exp chain) that round 12
// showed dominates (per-SIMD VALU issue only ~31%; VALUBusy 75% is the
// 4-SIMD union). Round 12 ran 2 sequential generations (512 WGs, 1/CU);
// this runs one.
// REGISTER LAW (r2/r9/r10/r12): arch VGPRs = waves_per_eu budget/2.
// (2,2) -> 128 arch. Demand ~132: the ~4 coldest values (biases) go to AGPR
// at negligible cost; weights stay architected. WRITE_SIZE is the spill
// canary: ~10.3 MB = output-only; >>10.5 MB means weights spilled.
__global__ __launch_bounds__(512)
__attribute__((amdgpu_waves_per_eu(2, 2)))
void gru_ae_kernel(
    const float* __restrict__ x,
    const float* __restrict__ eWih, const float* __restrict__ eWhh,
    const float* __restrict__ ebih, const float* __restrict__ ebhh,
    const float* __restrict__ efcW, const float* __restrict__ efcb,
    const float* __restrict__ dfcW, const float* __restrict__ dfcb,
    const float* __restrict__ dWih, const float* __restrict__ dWhh,
    const float* __restrict__ dbih, const float* __restrict__ dbhh,
    const float* __restrict__ oW, const float* __restrict__ ob,
    float* __restrict__ out)
{
    __shared__ __align__(16) float henc[2][2][HP4];  // [pingpong][row][gapped]
    __shared__ __align__(16) float hs[2][32][HP4];   // [row][slot][gapped]
    __shared__ __align__(16) float hdi[2][HP4];      // [row][gapped]
    __shared__ float zl[2][Ln];                      // latent z per row

    const int tid = threadIdx.x;
    const int j   = tid >> 2;       // hidden index 0..127
    const int kq  = tid & 3;        // K-quarter 0..3
    const int b0  = blockIdx.x * 2; // rows b0, b0+1
    const int koff = kq * 32;       // global float offset of quarter
    const int klds = kq * QP;       // gapped LDS offset of quarter

    // ---- encoder W_hh quarter-rows into registers (96 VGPRs, row-shared) ----
    float4 wr[8], wz[8], wn[8];
    {
        const float4* p0 = (const float4*)(eWhh + (size_t)j * Hd + koff);
        const float4* p1 = (const float4*)(eWhh + (size_t)(Hd + j) * Hd + koff);
        const float4* p2 = (const float4*)(eWhh + (size_t)(2 * Hd + j) * Hd + koff);
#pragma unroll
        for (int k = 0; k < 8; ++k) { wr[k] = p0[k]; wz[k] = p1[k]; wn[k] = p2[k]; }
    }
    // x-projection split across the quad: kq0 d={0,1}, kq1 d={2,3}, kq2 d={4}, kq3 none
    const int d0s = (kq == 1) ? 2 : (kq == 2) ? 4 : 0;
    const int inc = (kq < 2) ? 1 : 0;
    const float m0 = (kq < 3) ? 1.f : 0.f, m1 = (kq < 2) ? 1.f : 0.f;
    float wxr0 = m0 * eWih[(size_t)j * Dn + d0s];
    float wxr1 = m1 * eWih[(size_t)j * Dn + d0s + inc];
    float wxz0 = m0 * eWih[(size_t)(Hd + j) * Dn + d0s];
    float wxz1 = m1 * eWih[(size_t)(Hd + j) * Dn + d0s + inc];
    float wxn0 = m0 * eWih[(size_t)(2 * Hd + j) * Dn + d0s];
    float wxn1 = m1 * eWih[(size_t)(2 * Hd + j) * Dn + d0s + inc];

    float bR = ebih[j] + ebhh[j];
    float bZ = ebih[Hd + j] + ebhh[Hd + j];
    float bihn = ebih[2 * Hd + j];
    float bhhn = ebhh[2 * Hd + j];

    if (tid < 2 * Hd) {
        const int rp = tid >> 7, f = tid & 127;
        henc[0][rp][GF(f)] = 0.f; henc[1][rp][GF(f)] = 0.f;
    }
    __syncthreads();

    float h0 = 0.f, h1 = 0.f;
    int p = 0;
    const float* xt0 = x + (size_t)b0 * Tn * Dn;
    const float* xt1 = xt0 + (size_t)Tn * Dn;

    // ================= encoder: 1024 steps, 2 rows/step, 1 barrier/step =====
#pragma unroll 1
    for (int t = 0; t < Tn; ++t) {
        // both rows' x pair: issued first, consumed after ~192 FMAs (hidden)
        float xa0 = xt0[d0s], xa1 = xt0[d0s + inc];
        float xb0 = xt1[d0s], xb1 = xt1[d0s + inc];
        xt0 += Dn; xt1 += Dn;

        const float4* hv0 = (const float4*)&henc[p][0][klds];
        const float4* hv1 = (const float4*)&henc[p][1][klds];
        float ar0 = 0.f, az0 = 0.f, nh0 = 0.f;
        float ar1 = 0.f, az1 = 0.f, nh1 = 0.f;
        QDOT(hv0, ar0, az0, nh0)
        QDOT(hv1, ar1, az1, nh1)

        ar0 = fmaf(wxr0, xa0, fmaf(wxr1, xa1, ar0));
        az0 = fmaf(wxz0, xa0, fmaf(wxz1, xa1, az0));
        float nx0 = fmaf(wxn0, xa0, wxn1 * xa1);
        ar1 = fmaf(wxr0, xb0, fmaf(wxr1, xb1, ar1));
        az1 = fmaf(wxz0, xb0, fmaf(wxz1, xb1, az1));
        float nx1 = fmaf(wxn0, xb0, wxn1 * xb1);
        RED4(ar0); RED4(az0); RED4(nh0); RED4(nx0);
        RED4(ar1); RED4(az1); RED4(nh1); RED4(nx1);

        float r0 = sigm(ar0 + bR), z0 = sigm(az0 + bZ);
        float n0 = tanh_fast(nx0 + bihn + r0 * (nh0 + bhhn));
        float hn0 = fmaf(z0, h0 - n0, n0);
        float r1 = sigm(ar1 + bR), z1 = sigm(az1 + bZ);
        float n1 = tanh_fast(nx1 + bihn + r1 * (nh1 + bhhn));
        float hn1 = fmaf(z1, h1 - n1, n1);
        h0 = hn0; h1 = hn1;
        if (!kq) { henc[p ^ 1][0][GF(j)] = hn0; henc[p ^ 1][1][GF(j)] = hn1; }
        __syncthreads();
        p ^= 1;
    }

    // ================= latent z (both rows) =================
    if (tid < 2 * Ln) {
        const int rp = tid >> 4, l = tid & 15;
        const float4* wp = (const float4*)(efcW + (size_t)l * Hd);
        float acc = efcb[l];
#pragma unroll
        for (int q = 0; q < 32; ++q) {
            float4 w4 = wp[q];
            float4 h4 = *(const float4*)&henc[p][rp][CF(q)];
            acc = fmaf(w4.x, h4.x, fmaf(w4.y, h4.y, fmaf(w4.z, h4.z, fmaf(w4.w, h4.w, acc))));
        }
        out[(size_t)Bn * Tn * Dn + (size_t)(b0 + rp) * Ln + l] = acc;
        zl[rp][l] = acc;
    }
    __syncthreads();

    // ================= h_dec_in = z @ dec_fc_W.T + dec_fc_b (both rows) =====
    if (tid < 2 * Hd) {
        const int rp = tid >> 7, f = tid & 127;
        const float4* wp = (const float4*)(dfcW + (size_t)f * Ln);
        float acc = dfcb[f];
#pragma unroll
        for (int l = 0; l < 4; ++l) {
            float4 w4 = wp[l];
            acc = fmaf(w4.x, zl[rp][4 * l + 0], acc);
            acc = fmaf(w4.y, zl[rp][4 * l + 1], acc);
            acc = fmaf(w4.z, zl[rp][4 * l + 2], acc);
            acc = fmaf(w4.w, zl[rp][4 * l + 3], acc);
        }
        hdi[rp][GF(f)] = acc;
    }
    __syncthreads();

    // ================= xp_dec for both rows (constant over decoder) =========
    float xdr0, xdz0, xdn0, xdr1, xdz1, xdn1;
    {
        const float4* p0 = (const float4*)(dWih + (size_t)j * Hd + koff);
        const float4* p1 = (const float4*)(dWih + (size_t)(Hd + j) * Hd + koff);
        const float4* p2 = (const float4*)(dWih + (size_t)(2 * Hd + j) * Hd + koff);
#pragma unroll
        for (int k = 0; k < 8; ++k) { wr[k] = p0[k]; wz[k] = p1[k]; wn[k] = p2[k]; }
        const float4* hv0 = (const float4*)&hdi[0][klds];
        const float4* hv1 = (const float4*)&hdi[1][klds];
        float a0 = 0.f, a1 = 0.f, a2 = 0.f, c0 = 0.f, c1 = 0.f, c2 = 0.f;
        QDOT(hv0, a0, a1, a2)
        QDOT(hv1, c0, c1, c2)
        RED4(a0); RED4(a1); RED4(a2); RED4(c0); RED4(c1); RED4(c2);
        const float br_ = dbih[j] + dbhh[j];
        const float bz_ = dbih[Hd + j] + dbhh[Hd + j];
        const float bn_ = dbih[2 * Hd + j];
        xdr0 = a0 + br_; xdz0 = a1 + bz_; xdn0 = a2 + bn_;
        xdr1 = c0 + br_; xdz1 = c1 + bz_; xdn1 = c2 + bn_;
        bhhn = dbhh[2 * Hd + j];
    }

    // ---- decoder W_hh quarter-rows ----
    {
        const float4* p0 = (const float4*)(dWhh + (size_t)j * Hd + koff);
        const float4* p1 = (const float4*)(dWhh + (size_t)(Hd + j) * Hd + koff);
        const float4* p2 = (const float4*)(dWhh + (size_t)(2 * Hd + j) * Hd + koff);
#pragma unroll
        for (int k = 0; k < 8; ++k) { wr[k] = p0[k]; wz[k] = p1[k]; wn[k] = p2[k]; }
    }

    if (tid < 2 * Hd) {
        const int rp = tid >> 7, f = tid & 127;
        hs[rp][31][GF(f)] = 0.f;   // "previous h" for decoder step 0
    }
    h0 = 0.f; h1 = 0.f;
    __syncthreads();

    // ================= decoder: 1024 steps, 2 rows/step, 32-step tiles ======
#pragma unroll 1
    for (int s0 = 0; s0 < Tn; s0 += 32) {
#pragma unroll 1
        for (int ss = 0; ss < 32; ++ss) {
            const int ip = (ss + 31) & 31;
            const float4* hv0 = (const float4*)&hs[0][ip][klds];
            const float4* hv1 = (const float4*)&hs[1][ip][klds];
            float ar0 = 0.f, az0 = 0.f, nh0 = 0.f;
            float ar1 = 0.f, az1 = 0.f, nh1 = 0.f;
            QDOT(hv0, ar0, az0, nh0)
            QDOT(hv1, ar1, az1, nh1)
            RED4(ar0); RED4(az0); RED4(nh0);
            RED4(ar1); RED4(az1); RED4(nh1);
            float r0 = sigm(xdr0 + ar0), z0 = sigm(xdz0 + az0);
            float n0 = tanh_fast(xdn0 + r0 * (nh0 + bhhn));
            float hn0 = fmaf(z0, h0 - n0, n0);
            float r1 = sigm(xdr1 + ar1), z1 = sigm(xdz1 + az1);
            float n1 = tanh_fast(xdn1 + r1 * (nh1 + bhhn));
            float hn1 = fmaf(z1, h1 - n1, n1);
            h0 = hn0; h1 = hn1;
            if (!kq) { hs[0][ss][GF(j)] = hn0; hs[1][ss][GF(j)] = hn1; }
            __syncthreads();
        }

        // ---- bulk recon projection, both rows (coalesced stores) ----
        if (tid < 320) {
            const int rowp = tid / 160, o = tid % 160;
            const int i = o / 5, d = o % 5;
            const float4* wrow = (const float4*)(oW + (size_t)d * Hd);
            float ac0 = ob[d], ac1 = 0.f;
#pragma unroll
            for (int q = 0; q < 32; q += 2) {
                const int qa = (q + i) & 31, qb = (q + 1 + i) & 31;
                float4 ha = *(const float4*)&hs[rowp][i][CF(qa)];
                float4 wa = wrow[qa];
                float4 hb = *(const float4*)&hs[rowp][i][CF(qb)];
                float4 wb = wrow[qb];
                ac0 = fmaf(wa.x, ha.x, fmaf(wa.y, ha.y, fmaf(wa.z, ha.z, fmaf(wa.w, ha.w, ac0))));
                ac1 = fmaf(wb.x, hb.x, fmaf(wb.y, hb.y, fmaf(wb.z, hb.z, fmaf(wb.w, hb.w, ac1))));
            }
            out[((size_t)(b0 + rowp) * Tn + s0 + i) * Dn + d] = ac0 + ac1;
        }
        __syncthreads();   // protect hs before next tile overwrites slots
    }
}

extern "C" void kernel_launch(void* const* d_in, const int* in_sizes, int n_in,
                              void* d_out, int out_size, void* d_ws, size_t ws_size,
                              hipStream_t stream) {
    const float* x    = (const float*)d_in[0];
    const float* eWih = (const float*)d_in[1];
    const float* eWhh = (const float*)d_in[2];
    const float* ebih = (const float*)d_in[3];
    const float* ebhh = (const float*)d_in[4];
    const float* efcW = (const float*)d_in[5];
    const float* efcb = (const float*)d_in[6];
    const float* dfcW = (const float*)d_in[7];
    const float* dfcb = (const float*)d_in[8];
    const float* dWih = (const float*)d_in[9];
    const float* dWhh = (const float*)d_in[10];
    const float* dbih = (const float*)d_in[11];
    const float* dbhh = (const float*)d_in[12];
    const float* oW   = (const float*)d_in[13];
    const float* ob   = (const float*)d_in[14];
    float* out = (float*)d_out;

    gru_ae_kernel<<<dim3(Bn / 2), dim3(512), 0, stream>>>(
        x, eWih, eWhh, ebih, ebhh, efcW, efcb, dfcW, dfcb,
        dWih, dWhh, dbih, dbhh, oW, ob, out);
}